// Round 1
// baseline (560.431 us; speedup 1.0000x reference)
//
#include <hip/hip_runtime.h>

typedef __attribute__((ext_vector_type(8))) short short8;
typedef __attribute__((ext_vector_type(8))) _Float16 half8;
typedef __attribute__((ext_vector_type(16))) float f32x16;
typedef __attribute__((ext_vector_type(4))) float f32x4;
typedef __attribute__((ext_vector_type(4))) unsigned short u16x4;
typedef __attribute__((ext_vector_type(8))) unsigned short u16x8;
typedef unsigned int u32;
typedef unsigned short u16;

#define B_ 8
#define H_ 8
#define N_ 2048
#define D_ 64
#define PSTR 72   // LDS row stride (shorts)
#define ELEMS 8388608             // B*H*N*D
#define WS_NEED (3ull * 16777216ull)

static __device__ inline u16 bfhi(float x) {
  u32 u = __float_as_uint(x);
  return (u16)((u + 0x7FFFu + ((u >> 16) & 1u)) >> 16);
}
static __device__ inline float bf2f(u16 h) { return __uint_as_float((u32)h << 16); }
static __device__ inline u16 h2u(_Float16 h) { union { _Float16 f; u16 u; } c; c.f = h; return c.u; }

// ---- fused prepass: K -> f16 (hi,lo) same layout; V -> [bh][d][key] f16 ----
__global__ __launch_bounds__(256) void conv_kv(
    const float* __restrict__ K, const float* __restrict__ V,
    u16* __restrict__ Khi, u16* __restrict__ Klo,
    u16* __restrict__ VThi) {
  const int kt = blockIdx.x, bh = blockIdx.y, tid = threadIdx.x;
  const size_t ib = (size_t)bh * N_ * D_ + (size_t)kt * 64 * D_;
  __shared__ float sT[64 * 68];
#pragma unroll
  for (int cc = 0; cc < 2; ++cc) {
    const int c = tid + cc * 256, row = c >> 3, seg = c & 7;
    f32x4 a  = *(const f32x4*)(K + ib + row * D_ + seg * 8);
    f32x4 b2 = *(const f32x4*)(K + ib + row * D_ + seg * 8 + 4);
    u16x8 h, l;
#pragma unroll
    for (int j = 0; j < 4; ++j) {
      _Float16 h0 = (_Float16)a[j];
      h[j] = h2u(h0); l[j] = h2u((_Float16)(a[j] - (float)h0));
      _Float16 h1 = (_Float16)b2[j];
      h[j + 4] = h2u(h1); l[j + 4] = h2u((_Float16)(b2[j] - (float)h1));
    }
    *(u16x8*)&Khi[ib + row * D_ + seg * 8] = h;
    *(u16x8*)&Klo[ib + row * D_ + seg * 8] = l;
    *(f32x4*)&sT[row * 68 + seg * 8]     = *(const f32x4*)(V + ib + row * D_ + seg * 8);
    *(f32x4*)&sT[row * 68 + seg * 8 + 4] = *(const f32x4*)(V + ib + row * D_ + seg * 8 + 4);
  }
  __syncthreads();
  const int d = tid >> 2, ks = tid & 3;   // 16 keys per thread, fixed d
  u16x8 h0, h1;
#pragma unroll
  for (int i = 0; i < 8; ++i) {
    h0[i] = h2u((_Float16)sT[(ks * 16 + i) * 68 + d]);
    h1[i] = h2u((_Float16)sT[(ks * 16 + i + 8) * 68 + d]);
  }
  const size_t ob = (size_t)bh * D_ * N_ + (size_t)d * N_ + (size_t)kt * 64 + ks * 16;
  *(u16x8*)&VThi[ob] = h0; *(u16x8*)&VThi[ob + 8] = h1;
}

// -------------------- main kernel: 128 q-rows per block ---------------------
__global__ __launch_bounds__(256, 4) void attn_mfma3(
    const float* __restrict__ Qg,
    const u16* __restrict__ Khi, const u16* __restrict__ Klo,
    const u16* __restrict__ VThi,
    const int* __restrict__ maskg, float* __restrict__ Og)
{
  const int qtile = blockIdx.x;   // 0..15 (128 q-rows each)
  const int bh = blockIdx.y, b = bh >> 3;
  const int tid = threadIdx.x, w = tid >> 6, lane = tid & 63;
  const int l32 = lane & 31, hl = lane >> 5;

  __shared__ short sKbuf[2 * 64 * PSTR];          // sKh | sKl ; sP overlays
  __shared__ short sVh[64 * PSTR];
  __shared__ float sM[64];
  short* const sKh = sKbuf;
  short* const sKl = sKbuf + 64 * PSTR;
  short* const sP  = sKbuf;                       // 128*PSTR == 2*64*PSTR

  // ---- Q fragments (f16 hi/lo) for my 32 q-rows (A: m=l32, k=s*16+hl*8+j) ----
  half8 qfh[4], qfl[4];
  {
    const float* qp = Qg + ((size_t)bh * N_ + qtile * 128 + w * 32 + l32) * D_ + hl * 8;
#pragma unroll
    for (int s = 0; s < 4; ++s) {
      f32x4 a = *(const f32x4*)(qp + s * 16);
      f32x4 c = *(const f32x4*)(qp + s * 16 + 4);
#pragma unroll
      for (int j = 0; j < 4; ++j) {
        _Float16 h0 = (_Float16)a[j];
        qfh[s][j] = h0; qfl[s][j] = (_Float16)(a[j] - (float)h0);
        _Float16 h1 = (_Float16)c[j];
        qfh[s][j + 4] = h1; qfl[s][j + 4] = (_Float16)(c[j] - (float)h1);
      }
    }
  }
  half8 ones;
#pragma unroll
  for (int j = 0; j < 8; ++j) ones[j] = (l32 == 0) ? (_Float16)1.f : (_Float16)0.f;

  f32x16 accO0, accO1, accD;
#pragma unroll
  for (int i = 0; i < 16; ++i) { accO0[i] = 0.f; accO1[i] = 0.f; accD[i] = 0.f; }

  const size_t kvb = (size_t)bh * N_ * D_;

  // ---- prologue prefetch of tile 0 (T14 async-stage split) ----
  short8 rKh[2], rKl[2], rVh[2];
  int mreg = 0;
#pragma unroll
  for (int cc = 0; cc < 2; ++cc) {
    const int c = tid + cc * 256, row = c >> 3, seg = c & 7;
    rKh[cc] = *(const short8*)&Khi[kvb + (size_t)row * D_ + seg * 8];
    rKl[cc] = *(const short8*)&Klo[kvb + (size_t)row * D_ + seg * 8];
    rVh[cc] = *(const short8*)&VThi[kvb + (size_t)row * N_ + seg * 8];
  }
  if (tid < 64) mreg = maskg[b * N_ + tid];

  for (int kt = 0; kt < N_ / 64; ++kt) {
    __syncthreads();   // (A) prev PV reads (incl. sP overlay, sVh) complete

    // ---- staging: write prefetched regs, pure b128 ds_writes ----
#pragma unroll
    for (int cc = 0; cc < 2; ++cc) {
      const int c = tid + cc * 256, row = c >> 3, seg = c & 7;
      const int lofs = row * PSTR + seg * 8;
      *(short8*)&sKh[lofs] = rKh[cc];
      *(short8*)&sKl[lofs] = rKl[cc];
      *(short8*)&sVh[lofs] = rVh[cc];
    }
    if (tid < 64) sM[tid] = mreg ? -16384.f : 0.f;  // exp2 bias
    __syncthreads();   // (B)

    // ---- S = Q K^T, both 32-key column halves (f16 hi/lo, 3 cross terms) ----
    f32x16 S0, S1;
#pragma unroll
    for (int i = 0; i < 16; ++i) { S0[i] = 0.f; S1[i] = 0.f; }
    __builtin_amdgcn_s_setprio(1);
#pragma unroll
    for (int s = 0; s < 4; ++s) {
      const int o0 = l32 * PSTR + s * 16 + hl * 8;
      half8 kfh = *(const half8*)&sKh[o0];
      half8 kfl = *(const half8*)&sKl[o0];
      S0 = __builtin_amdgcn_mfma_f32_32x32x16_f16(qfh[s], kfh, S0, 0, 0, 0);
      S0 = __builtin_amdgcn_mfma_f32_32x32x16_f16(qfl[s], kfh, S0, 0, 0, 0);
      S0 = __builtin_amdgcn_mfma_f32_32x32x16_f16(qfh[s], kfl, S0, 0, 0, 0);
      const int o1 = (32 + l32) * PSTR + s * 16 + hl * 8;
      half8 kgh = *(const half8*)&sKh[o1];
      half8 kgl = *(const half8*)&sKl[o1];
      S1 = __builtin_amdgcn_mfma_f32_32x32x16_f16(qfh[s], kgh, S1, 0, 0, 0);
      S1 = __builtin_amdgcn_mfma_f32_32x32x16_f16(qfl[s], kgh, S1, 0, 0, 0);
      S1 = __builtin_amdgcn_mfma_f32_32x32x16_f16(qfh[s], kgl, S1, 0, 0, 0);
    }
    __builtin_amdgcn_s_setprio(0);
    __syncthreads();   // (C) all QK reads of sK done; sP overlay now writable

    // ---- softmax numerator p = exp(10*tanh(s/8) - 10), mask as exp2 bias ----
    const float bias0 = sM[l32], bias1 = sM[32 + l32];
#pragma unroll
    for (int r = 0; r < 16; ++r) {
      const int row = w * 32 + (r & 3) + 8 * (r >> 2) + 4 * hl;  // C-layout row
      {
        float s  = S0[r];
        float z  = __builtin_amdgcn_exp2f(fabsf(s) * -0.36067376022224087f);
        float nu = (s >= 0.f) ? z : 1.f;
        float e  = __builtin_fmaf(nu * __builtin_amdgcn_rcpf(1.f + z),
                                  -28.853900817779268f, bias0);
        float p  = __builtin_amdgcn_exp2f(e);
        sP[row * PSTR + l32] = (short)h2u((_Float16)p);
      }
      {
        float s  = S1[r];
        float z  = __builtin_amdgcn_exp2f(fabsf(s) * -0.36067376022224087f);
        float nu = (s >= 0.f) ? z : 1.f;
        float e  = __builtin_fmaf(nu * __builtin_amdgcn_rcpf(1.f + z),
                                  -28.853900817779268f, bias1);
        float p  = __builtin_amdgcn_exp2f(e);
        sP[row * PSTR + 32 + l32] = (short)h2u((_Float16)p);
      }
    }

    // ---- prefetch next k-tile into registers (S0/S1 dead: pressure ok) ----
    if (kt + 1 < N_ / 64) {
      const int k0n = (kt + 1) * 64;
#pragma unroll
      for (int cc = 0; cc < 2; ++cc) {
        const int c = tid + cc * 256, row = c >> 3, seg = c & 7;
        rKh[cc] = *(const short8*)&Khi[kvb + (size_t)(k0n + row) * D_ + seg * 8];
        rKl[cc] = *(const short8*)&Klo[kvb + (size_t)(k0n + row) * D_ + seg * 8];
        rVh[cc] = *(const short8*)&VThi[kvb + (size_t)row * N_ + k0n + seg * 8];
      }
      if (tid < 64) mreg = maskg[b * N_ + k0n + tid];
    }
    __syncthreads();   // (D) P visible

    // ---- O += P V (both d-halves, single f16 V); den += P * ones ----
    __builtin_amdgcn_s_setprio(1);
#pragma unroll
    for (int s = 0; s < 4; ++s) {
      half8 pf = *(const half8*)&sP[(w * 32 + l32) * PSTR + s * 16 + hl * 8];
      const int o0 = l32 * PSTR + s * 16 + hl * 8;          // d = l32
      half8 v0 = *(const half8*)&sVh[o0];
      accO0 = __builtin_amdgcn_mfma_f32_32x32x16_f16(pf, v0, accO0, 0, 0, 0);
      const int o1 = (32 + l32) * PSTR + s * 16 + hl * 8;   // d = 32 + l32
      half8 v1 = *(const half8*)&sVh[o1];
      accO1 = __builtin_amdgcn_mfma_f32_32x32x16_f16(pf, v1, accO1, 0, 0, 0);
      accD  = __builtin_amdgcn_mfma_f32_32x32x16_f16(pf, ones, accD, 0, 0, 0);
    }
    __builtin_amdgcn_s_setprio(0);
  }

  // ---- normalize and store ----
  const size_t obase = (size_t)bh * N_ + qtile * 128 + w * 32;
#pragma unroll
  for (int r = 0; r < 16; ++r) {
    float den = __shfl(accD[r], lane & 32);   // col 0 of my half holds row-sum
    float inv = (den > 0.f) ? (1.f / den) : 0.f;
    const int row = (r & 3) + 8 * (r >> 2) + 4 * hl;
    Og[(obase + row) * D_ + l32]      = accO0[r] * inv;
    Og[(obase + row) * D_ + 32 + l32] = accO1[r] * inv;
  }
}

// --------------- fallback (R9, proven): in-kernel conversions ---------------
__global__ __launch_bounds__(256, 3) void attn_mfma(
    const float* __restrict__ Qg, const float* __restrict__ Kg,
    const float* __restrict__ Vg, const int* __restrict__ maskg,
    float* __restrict__ Og)
{
  const int qtile = blockIdx.x;
  const int bh    = blockIdx.y;
  const int b     = bh >> 3;
  const int tid   = threadIdx.x;
  const int w     = tid >> 6;
  const int lane  = tid & 63;
  const int l32   = lane & 31;
  const int hl    = lane >> 5;
  const int qh    = w >> 1;
  const int kh    = w & 1;

  __shared__ short sKh[64 * PSTR], sKl[64 * PSTR];
  __shared__ short sVh[64 * PSTR], sVl[64 * PSTR];
  __shared__ short sP [64 * PSTR];
  __shared__ float sM[64];

  short8 qfh[4], qfl[4];
  {
    const float* qp = Qg + ((size_t)bh * N_ + qtile * 64 + qh * 32 + l32) * D_ + hl * 8;
#pragma unroll
    for (int s = 0; s < 4; ++s) {
      f32x4 a = *(const f32x4*)(qp + s * 16);
      f32x4 c = *(const f32x4*)(qp + s * 16 + 4);
#pragma unroll
      for (int j = 0; j < 4; ++j) {
        u16 h0 = bfhi(a[j]);
        qfh[s][j] = (short)h0;
        qfl[s][j] = (short)bfhi(a[j] - bf2f(h0));
        u16 h1 = bfhi(c[j]);
        qfh[s][j + 4] = (short)h1;
        qfl[s][j + 4] = (short)bfhi(c[j] - bf2f(h1));
      }
    }
  }
  short8 ones;
#pragma unroll
  for (int j = 0; j < 8; ++j) ones[j] = (short)((l32 == 0) ? 0x3F80 : 0);
  f32x16 accO, accD;
#pragma unroll
  for (int i = 0; i < 16; ++i) { accO[i] = 0.f; accD[i] = 0.f; }
  const size_t kvbase = (size_t)bh * N_ * D_;

  for (int kt = 0; kt < N_ / 64; ++kt) {
    const int k0 = kt * 64;
    __syncthreads();
    {
      const int row = tid >> 2, seg = tid & 3;
      const float* kp = Kg + kvbase + (size_t)(k0 + row) * D_ + seg * 16;
      short8 h0, h1, l0, l1;
#pragma unroll
      for (int i2 = 0; i2 < 2; ++i2) {
        f32x4 t0 = *(const f32x4*)(kp + i2 * 8);
        f32x4 t1 = *(const f32x4*)(kp + i2 * 8 + 4);
#pragma unroll
        for (int j = 0; j < 4; ++j) {
          u16 ha = bfhi(t0[j]); u16 la = bfhi(t0[j] - bf2f(ha));
          u16 hb = bfhi(t1[j]); u16 lb = bfhi(t1[j] - bf2f(hb));
          if (i2 == 0) { h0[j]=(short)ha; l0[j]=(short)la; h0[j+4]=(short)hb; l0[j+4]=(short)lb; }
          else         { h1[j]=(short)ha; l1[j]=(short)la; h1[j+4]=(short)hb; l1[j+4]=(short)lb; }
        }
      }
      *(short8*)&sKh[row * PSTR + seg * 16]     = h0;
      *(short8*)&sKh[row * PSTR + seg * 16 + 8] = h1;
      *(short8*)&sKl[row * PSTR + seg * 16]     = l0;
      *(short8*)&sKl[row * PSTR + seg * 16 + 8] = l1;
    }
    {
      const float* vp = Vg + kvbase + (size_t)(k0 + w * 16) * D_ + lane;
      float vv[16];
#pragma unroll
      for (int kk = 0; kk < 16; ++kk) vv[kk] = vp[(size_t)kk * D_];
      short8 h0, h1, l0, l1;
#pragma unroll
      for (int kk = 0; kk < 8; ++kk) {
        u16 ha = bfhi(vv[kk]);     h0[kk]=(short)ha; l0[kk]=(short)bfhi(vv[kk]-bf2f(ha));
        u16 hb = bfhi(vv[kk + 8]); h1[kk]=(short)hb; l1[kk]=(short)bfhi(vv[kk+8]-bf2f(hb));
      }
      *(short8*)&sVh[lane * PSTR + w * 16]     = h0;
      *(short8*)&sVh[lane * PSTR + w * 16 + 8] = h1;
      *(short8*)&sVl[lane * PSTR + w * 16]     = l0;
      *(short8*)&sVl[lane * PSTR + w * 16 + 8] = l1;
    }
    if (tid < 64) sM[tid] = maskg[b * N_ + k0 + tid] ? 0.f : 1.f;
    __syncthreads();

    f32x16 S;
#pragma unroll
    for (int i = 0; i < 16; ++i) S[i] = 0.f;
#pragma unroll
    for (int s = 0; s < 4; ++s) {
      const int off = (kh * 32 + l32) * PSTR + s * 16 + hl * 8;
      short8 kfh = *(const short8*)&sKh[off];
      short8 kfl = *(const short8*)&sKl[off];
      S = __builtin_amdgcn_mfma_f32_32x32x16_bf16(qfh[s], kfh, S, 0, 0, 0);
      S = __builtin_amdgcn_mfma_f32_32x32x16_bf16(qfl[s], kfh, S, 0, 0, 0);
      S = __builtin_amdgcn_mfma_f32_32x32x16_bf16(qfh[s], kfl, S, 0, 0, 0);
    }
    const float pm = sM[kh * 32 + l32];
#pragma unroll
    for (int r = 0; r < 16; ++r) {
      float x  = S[r] * 0.125f;
      float ax = fminf(fabsf(x), 30.f);
      float z  = __builtin_amdgcn_exp2f(ax * -2.8853900817779268f);
      float nu = (x >= 0.f) ? z : 1.f;
      float e  = nu * __builtin_amdgcn_rcpf(1.f + z) * -28.853900817779268f;
      float p  = __builtin_amdgcn_exp2f(e) * pm;
      const int row = qh * 32 + (r & 3) + 8 * (r >> 2) + 4 * hl;
      sP[row * PSTR + kh * 32 + l32] = (short)bfhi(p);
    }
    __syncthreads();
#pragma unroll
    for (int s = 0; s < 4; ++s) {
      short8 pf  = *(const short8*)&sP[(qh * 32 + l32) * PSTR + s * 16 + hl * 8];
      const int voff = (kh * 32 + l32) * PSTR + s * 16 + hl * 8;
      short8 vfh = *(const short8*)&sVh[voff];
      short8 vfl = *(const short8*)&sVl[voff];
      accO = __builtin_amdgcn_mfma_f32_32x32x16_bf16(pf, vfh, accO, 0, 0, 0);
      accO = __builtin_amdgcn_mfma_f32_32x32x16_bf16(pf, vfl, accO, 0, 0, 0);
      accD = __builtin_amdgcn_mfma_f32_32x32x16_bf16(pf, ones, accD, 0, 0, 0);
    }
  }
  const size_t obase = (size_t)bh * N_ + qtile * 64 + qh * 32;
#pragma unroll
  for (int r = 0; r < 16; ++r) {
    float den = __shfl(accD[r], lane & 32);
    float inv = (den > 0.f) ? (1.f / den) : 0.f;
    const int row = (r & 3) + 8 * (r >> 2) + 4 * hl;
    Og[(obase + row) * D_ + kh * 32 + l32] = accO[r] * inv;
  }
}

extern "C" void kernel_launch(void* const* d_in, const int* in_sizes, int n_in,
                              void* d_out, int out_size, void* d_ws, size_t ws_size,
                              hipStream_t stream) {
  const float* Q = (const float*)d_in[0];
  const float* K = (const float*)d_in[1];
  const float* V = (const float*)d_in[2];
  const int* mask = (const int*)d_in[3];
  float* out = (float*)d_out;
  dim3 block(256);
  if (ws_size >= (size_t)WS_NEED) {
    u16* wsp  = (u16*)d_ws;
    u16* Khi  = wsp;
    u16* Klo  = wsp + ELEMS;
    u16* VThi = wsp + 2 * (size_t)ELEMS;
    conv_kv<<<dim3(32, 64), block, 0, stream>>>(K, V, Khi, Klo, VThi);
    attn_mfma3<<<dim3(16, 64), block, 0, stream>>>(Q, Khi, Klo, VThi, mask, out);
  } else {
    attn_mfma<<<dim3(32, 64), block, 0, stream>>>(Q, K, V, mask, out);
  }
}

// Round 2
// 268.397 us; speedup vs baseline: 2.0881x; 2.0881x over previous
//
#include <hip/hip_runtime.h>

typedef __attribute__((ext_vector_type(8))) short short8;
typedef __attribute__((ext_vector_type(8))) _Float16 half8;
typedef __attribute__((ext_vector_type(16))) float f32x16;
typedef __attribute__((ext_vector_type(4))) float f32x4;
typedef __attribute__((ext_vector_type(4))) unsigned short u16x4;
typedef __attribute__((ext_vector_type(8))) unsigned short u16x8;
typedef unsigned int u32;
typedef unsigned short u16;

#define B_ 8
#define H_ 8
#define N_ 2048
#define D_ 64
#define PSTR 72   // LDS row stride (shorts)
#define ELEMS 8388608             // B*H*N*D
#define WS_NEED (3ull * 16777216ull + 65536ull + 4096ull)

static __device__ inline u16 bfhi(float x) {
  u32 u = __float_as_uint(x);
  return (u16)((u + 0x7FFFu + ((u >> 16) & 1u)) >> 16);
}
static __device__ inline float bf2f(u16 h) { return __uint_as_float((u32)h << 16); }
static __device__ inline u16 h2u(_Float16 h) { union { _Float16 f; u16 u; } c; c.f = h; return c.u; }

// ---- pass 0: per-batch stream compaction of unmasked key indices ----------
__global__ __launch_bounds__(256) void mask_scan(
    const int* __restrict__ maskg, int* __restrict__ idx, int* __restrict__ cnt) {
  const int b = blockIdx.x, tid = threadIdx.x;
  __shared__ int sc[256];
  const int n0 = tid * 8;
  u32 bits = 0;
  int c = 0;
#pragma unroll
  for (int i = 0; i < 8; ++i) {
    if (maskg[b * N_ + n0 + i] == 0) { bits |= (1u << i); ++c; }  // mask==0 -> kept
  }
  sc[tid] = c;
  __syncthreads();
  for (int off = 1; off < 256; off <<= 1) {   // Hillis-Steele inclusive scan
    int v = (tid >= off) ? sc[tid - off] : 0;
    __syncthreads();
    sc[tid] += v;
    __syncthreads();
  }
  const int total = sc[255];
  int o = sc[tid] - c;                        // exclusive offset
#pragma unroll
  for (int i = 0; i < 8; ++i)
    if (bits & (1u << i)) idx[b * N_ + (o++)] = n0 + i;
  if (tid < 64) {                             // pad last tile with -1 sentinels
    int j = total + tid;
    if (j < ((total + 63) & ~63)) idx[b * N_ + j] = -1;
  }
  if (tid == 0) cnt[b] = total;
}

// ---- pass 1: compacted gather + convert: K -> f16 (hi,lo); V -> [bh][d][j] ----
__global__ __launch_bounds__(256) void conv_kv2(
    const float* __restrict__ K, const float* __restrict__ V,
    const int* __restrict__ idx, const int* __restrict__ cnt,
    u16* __restrict__ Khi, u16* __restrict__ Klo, u16* __restrict__ VThi) {
  const int kt = blockIdx.x, bh = blockIdx.y, b = bh >> 3, tid = threadIdx.x;
  const int cntb = cnt[b];
  const int nt = (cntb + 63) >> 6;
  if (kt >= nt) return;
  __shared__ float sT[64 * 68];
  __shared__ int sIdx[64];
  if (tid < 64) sIdx[tid] = idx[b * N_ + kt * 64 + tid];
  __syncthreads();
  const size_t ibh = (size_t)bh * N_ * D_;
  const size_t okb = ibh + (size_t)kt * 64 * D_;   // compacted K row base
#pragma unroll
  for (int cc = 0; cc < 2; ++cc) {
    const int c = tid + cc * 256, row = c >> 3, seg = c & 7;
    const int n = sIdx[row];
    f32x4 a, b2, va, vb;
    if (n >= 0) {
      const float* kp = K + ibh + (size_t)n * D_ + seg * 8;
      a  = *(const f32x4*)kp;
      b2 = *(const f32x4*)(kp + 4);
      const float* vp = V + ibh + (size_t)n * D_ + seg * 8;
      va = *(const f32x4*)vp;
      vb = *(const f32x4*)(vp + 4);
    } else {
#pragma unroll
      for (int j = 0; j < 4; ++j) { a[j] = 0.f; b2[j] = 0.f; va[j] = 0.f; vb[j] = 0.f; }
    }
    u16x8 h, l;
#pragma unroll
    for (int j = 0; j < 4; ++j) {
      _Float16 h0 = (_Float16)a[j];
      h[j] = h2u(h0); l[j] = h2u((_Float16)(a[j] - (float)h0));
      _Float16 h1 = (_Float16)b2[j];
      h[j + 4] = h2u(h1); l[j + 4] = h2u((_Float16)(b2[j] - (float)h1));
    }
    *(u16x8*)&Khi[okb + row * D_ + seg * 8] = h;
    *(u16x8*)&Klo[okb + row * D_ + seg * 8] = l;
    *(f32x4*)&sT[row * 68 + seg * 8]     = va;
    *(f32x4*)&sT[row * 68 + seg * 8 + 4] = vb;
  }
  __syncthreads();
  const int d = tid >> 2, ks = tid & 3;   // 16 compacted keys per thread, fixed d
  u16x8 h0, h1;
#pragma unroll
  for (int i = 0; i < 8; ++i) {
    h0[i] = h2u((_Float16)sT[(ks * 16 + i) * 68 + d]);
    h1[i] = h2u((_Float16)sT[(ks * 16 + i + 8) * 68 + d]);
  }
  const size_t ob = (size_t)bh * D_ * N_ + (size_t)d * N_ + (size_t)kt * 64 + ks * 16;
  *(u16x8*)&VThi[ob] = h0; *(u16x8*)&VThi[ob + 8] = h1;
}

// -------------------- main kernel: 128 q-rows per block ---------------------
__global__ __launch_bounds__(256, 4) void attn_mfma3(
    const float* __restrict__ Qg,
    const u16* __restrict__ Khi, const u16* __restrict__ Klo,
    const u16* __restrict__ VThi,
    const int* __restrict__ cnt, float* __restrict__ Og)
{
  const int qtile = blockIdx.x;   // 0..15 (128 q-rows each)
  const int bh = blockIdx.y, b = bh >> 3;
  const int tid = threadIdx.x, w = tid >> 6, lane = tid & 63;
  const int l32 = lane & 31, hl = lane >> 5;
  const int cntb = cnt[b];
  const int nt = (cntb + 63) >> 6;

  __shared__ short sKbuf[2 * 64 * PSTR];          // sKh | sKl ; sP overlays
  __shared__ short sVh[64 * PSTR];
  __shared__ float sM[64];
  short* const sKh = sKbuf;
  short* const sKl = sKbuf + 64 * PSTR;
  short* const sP  = sKbuf;                       // 128*PSTR == 2*64*PSTR

  // ---- Q fragments (f16 hi/lo) for my 32 q-rows (A: m=l32, k=s*16+hl*8+j) ----
  half8 qfh[4], qfl[4];
  {
    const float* qp = Qg + ((size_t)bh * N_ + qtile * 128 + w * 32 + l32) * D_ + hl * 8;
#pragma unroll
    for (int s = 0; s < 4; ++s) {
      f32x4 a = *(const f32x4*)(qp + s * 16);
      f32x4 c = *(const f32x4*)(qp + s * 16 + 4);
#pragma unroll
      for (int j = 0; j < 4; ++j) {
        _Float16 h0 = (_Float16)a[j];
        qfh[s][j] = h0; qfl[s][j] = (_Float16)(a[j] - (float)h0);
        _Float16 h1 = (_Float16)c[j];
        qfh[s][j + 4] = h1; qfl[s][j + 4] = (_Float16)(c[j] - (float)h1);
      }
    }
  }
  half8 ones;
#pragma unroll
  for (int j = 0; j < 8; ++j) ones[j] = (l32 == 0) ? (_Float16)1.f : (_Float16)0.f;

  f32x16 accO0, accO1, accD;
#pragma unroll
  for (int i = 0; i < 16; ++i) { accO0[i] = 0.f; accO1[i] = 0.f; accD[i] = 0.f; }

  const size_t kvb = (size_t)bh * N_ * D_;

  for (int kt = 0; kt < nt; ++kt) {
    const int k0 = kt * 64;
    __syncthreads();   // (A) prev PV reads (incl. sP overlay) complete

    // ---- staging: global -> reg -> LDS, pure b128 copies ----
#pragma unroll
    for (int cc = 0; cc < 2; ++cc) {
      const int c = tid + cc * 256, row = c >> 3, seg = c & 7;
      const int lofs = row * PSTR + seg * 8;
      const size_t kofs = kvb + (size_t)(k0 + row) * D_ + seg * 8;
      *(short8*)&sKh[lofs] = *(const short8*)&Khi[kofs];
      *(short8*)&sKl[lofs] = *(const short8*)&Klo[kofs];
      const size_t vofs = kvb + (size_t)row * N_ + k0 + seg * 8;
      *(short8*)&sVh[lofs] = *(const short8*)&VThi[vofs];
    }
    if (tid < 64) sM[tid] = (k0 + tid < cntb) ? 0.f : -16384.f;  // pad -> p=0
    __syncthreads();   // (B)

    // ---- S = Q K^T, both 32-key column halves (f16 hi/lo, 3 cross terms) ----
    f32x16 S0, S1;
#pragma unroll
    for (int i = 0; i < 16; ++i) { S0[i] = 0.f; S1[i] = 0.f; }
    __builtin_amdgcn_s_setprio(1);
#pragma unroll
    for (int s = 0; s < 4; ++s) {
      const int o0 = l32 * PSTR + s * 16 + hl * 8;
      half8 kfh = *(const half8*)&sKh[o0];
      half8 kfl = *(const half8*)&sKl[o0];
      S0 = __builtin_amdgcn_mfma_f32_32x32x16_f16(qfh[s], kfh, S0, 0, 0, 0);
      S0 = __builtin_amdgcn_mfma_f32_32x32x16_f16(qfl[s], kfh, S0, 0, 0, 0);
      S0 = __builtin_amdgcn_mfma_f32_32x32x16_f16(qfh[s], kfl, S0, 0, 0, 0);
      const int o1 = (32 + l32) * PSTR + s * 16 + hl * 8;
      half8 kgh = *(const half8*)&sKh[o1];
      half8 kgl = *(const half8*)&sKl[o1];
      S1 = __builtin_amdgcn_mfma_f32_32x32x16_f16(qfh[s], kgh, S1, 0, 0, 0);
      S1 = __builtin_amdgcn_mfma_f32_32x32x16_f16(qfl[s], kgh, S1, 0, 0, 0);
      S1 = __builtin_amdgcn_mfma_f32_32x32x16_f16(qfh[s], kgl, S1, 0, 0, 0);
    }
    __builtin_amdgcn_s_setprio(0);
    __syncthreads();   // (C) all QK reads of sK done; sP overlay now writable

    // ---- softmax numerator p = exp(10*tanh(s/8) - 10), pad as exp2 bias ----
    const float bias0 = sM[l32], bias1 = sM[32 + l32];
#pragma unroll
    for (int r = 0; r < 16; ++r) {
      const int row = w * 32 + (r & 3) + 8 * (r >> 2) + 4 * hl;  // C-layout row
      {
        float s  = S0[r];
        float z  = __builtin_amdgcn_exp2f(fabsf(s) * -0.36067376022224087f);
        float nu = (s >= 0.f) ? z : 1.f;
        float e  = __builtin_fmaf(nu * __builtin_amdgcn_rcpf(1.f + z),
                                  -28.853900817779268f, bias0);
        float p  = __builtin_amdgcn_exp2f(e);
        sP[row * PSTR + l32] = (short)h2u((_Float16)p);
      }
      {
        float s  = S1[r];
        float z  = __builtin_amdgcn_exp2f(fabsf(s) * -0.36067376022224087f);
        float nu = (s >= 0.f) ? z : 1.f;
        float e  = __builtin_fmaf(nu * __builtin_amdgcn_rcpf(1.f + z),
                                  -28.853900817779268f, bias1);
        float p  = __builtin_amdgcn_exp2f(e);
        sP[row * PSTR + 32 + l32] = (short)h2u((_Float16)p);
      }
    }
    __syncthreads();   // (D) P visible

    // ---- O += P V (both d-halves, single f16 V); den += P * ones ----
    __builtin_amdgcn_s_setprio(1);
#pragma unroll
    for (int s = 0; s < 4; ++s) {
      half8 pf = *(const half8*)&sP[(w * 32 + l32) * PSTR + s * 16 + hl * 8];
      const int o0 = l32 * PSTR + s * 16 + hl * 8;          // d = l32
      half8 v0 = *(const half8*)&sVh[o0];
      accO0 = __builtin_amdgcn_mfma_f32_32x32x16_f16(pf, v0, accO0, 0, 0, 0);
      const int o1 = (32 + l32) * PSTR + s * 16 + hl * 8;   // d = 32 + l32
      half8 v1 = *(const half8*)&sVh[o1];
      accO1 = __builtin_amdgcn_mfma_f32_32x32x16_f16(pf, v1, accO1, 0, 0, 0);
      accD  = __builtin_amdgcn_mfma_f32_32x32x16_f16(pf, ones, accD, 0, 0, 0);
    }
    __builtin_amdgcn_s_setprio(0);
  }

  // ---- normalize and store ----
  const size_t obase = (size_t)bh * N_ + qtile * 128 + w * 32;
#pragma unroll
  for (int r = 0; r < 16; ++r) {
    float den = __shfl(accD[r], lane & 32);   // col 0 of my half holds row-sum
    float inv = (den > 0.f) ? (1.f / den) : 0.f;
    const int row = (r & 3) + 8 * (r >> 2) + 4 * hl;
    Og[(obase + row) * D_ + l32]      = accO0[r] * inv;
    Og[(obase + row) * D_ + 32 + l32] = accO1[r] * inv;
  }
}

// --------------- fallback (R9, proven): in-kernel conversions ---------------
__global__ __launch_bounds__(256, 3) void attn_mfma(
    const float* __restrict__ Qg, const float* __restrict__ Kg,
    const float* __restrict__ Vg, const int* __restrict__ maskg,
    float* __restrict__ Og)
{
  const int qtile = blockIdx.x;
  const int bh    = blockIdx.y;
  const int b     = bh >> 3;
  const int tid   = threadIdx.x;
  const int w     = tid >> 6;
  const int lane  = tid & 63;
  const int l32   = lane & 31;
  const int hl    = lane >> 5;
  const int qh    = w >> 1;
  const int kh    = w & 1;

  __shared__ short sKh[64 * PSTR], sKl[64 * PSTR];
  __shared__ short sVh[64 * PSTR], sVl[64 * PSTR];
  __shared__ short sP [64 * PSTR];
  __shared__ float sM[64];

  short8 qfh[4], qfl[4];
  {
    const float* qp = Qg + ((size_t)bh * N_ + qtile * 64 + qh * 32 + l32) * D_ + hl * 8;
#pragma unroll
    for (int s = 0; s < 4; ++s) {
      f32x4 a = *(const f32x4*)(qp + s * 16);
      f32x4 c = *(const f32x4*)(qp + s * 16 + 4);
#pragma unroll
      for (int j = 0; j < 4; ++j) {
        u16 h0 = bfhi(a[j]);
        qfh[s][j] = (short)h0;
        qfl[s][j] = (short)bfhi(a[j] - bf2f(h0));
        u16 h1 = bfhi(c[j]);
        qfh[s][j + 4] = (short)h1;
        qfl[s][j + 4] = (short)bfhi(c[j] - bf2f(h1));
      }
    }
  }
  short8 ones;
#pragma unroll
  for (int j = 0; j < 8; ++j) ones[j] = (short)((l32 == 0) ? 0x3F80 : 0);
  f32x16 accO, accD;
#pragma unroll
  for (int i = 0; i < 16; ++i) { accO[i] = 0.f; accD[i] = 0.f; }
  const size_t kvbase = (size_t)bh * N_ * D_;

  for (int kt = 0; kt < N_ / 64; ++kt) {
    const int k0 = kt * 64;
    __syncthreads();
    {
      const int row = tid >> 2, seg = tid & 3;
      const float* kp = Kg + kvbase + (size_t)(k0 + row) * D_ + seg * 16;
      short8 h0, h1, l0, l1;
#pragma unroll
      for (int i2 = 0; i2 < 2; ++i2) {
        f32x4 t0 = *(const f32x4*)(kp + i2 * 8);
        f32x4 t1 = *(const f32x4*)(kp + i2 * 8 + 4);
#pragma unroll
        for (int j = 0; j < 4; ++j) {
          u16 ha = bfhi(t0[j]); u16 la = bfhi(t0[j] - bf2f(ha));
          u16 hb = bfhi(t1[j]); u16 lb = bfhi(t1[j] - bf2f(hb));
          if (i2 == 0) { h0[j]=(short)ha; l0[j]=(short)la; h0[j+4]=(short)hb; l0[j+4]=(short)lb; }
          else         { h1[j]=(short)ha; l1[j]=(short)la; h1[j+4]=(short)hb; l1[j+4]=(short)lb; }
        }
      }
      *(short8*)&sKh[row * PSTR + seg * 16]     = h0;
      *(short8*)&sKh[row * PSTR + seg * 16 + 8] = h1;
      *(short8*)&sKl[row * PSTR + seg * 16]     = l0;
      *(short8*)&sKl[row * PSTR + seg * 16 + 8] = l1;
    }
    {
      const float* vp = Vg + kvbase + (size_t)(k0 + w * 16) * D_ + lane;
      float vv[16];
#pragma unroll
      for (int kk = 0; kk < 16; ++kk) vv[kk] = vp[(size_t)kk * D_];
      short8 h0, h1, l0, l1;
#pragma unroll
      for (int kk = 0; kk < 8; ++kk) {
        u16 ha = bfhi(vv[kk]);     h0[kk]=(short)ha; l0[kk]=(short)bfhi(vv[kk]-bf2f(ha));
        u16 hb = bfhi(vv[kk + 8]); h1[kk]=(short)hb; l1[kk]=(short)bfhi(vv[kk+8]-bf2f(hb));
      }
      *(short8*)&sVh[lane * PSTR + w * 16]     = h0;
      *(short8*)&sVh[lane * PSTR + w * 16 + 8] = h1;
      *(short8*)&sVl[lane * PSTR + w * 16]     = l0;
      *(short8*)&sVl[lane * PSTR + w * 16 + 8] = l1;
    }
    if (tid < 64) sM[tid] = maskg[b * N_ + k0 + tid] ? 0.f : 1.f;
    __syncthreads();

    f32x16 S;
#pragma unroll
    for (int i = 0; i < 16; ++i) S[i] = 0.f;
#pragma unroll
    for (int s = 0; s < 4; ++s) {
      const int off = (kh * 32 + l32) * PSTR + s * 16 + hl * 8;
      short8 kfh = *(const short8*)&sKh[off];
      short8 kfl = *(const short8*)&sKl[off];
      S = __builtin_amdgcn_mfma_f32_32x32x16_bf16(qfh[s], kfh, S, 0, 0, 0);
      S = __builtin_amdgcn_mfma_f32_32x32x16_bf16(qfl[s], kfh, S, 0, 0, 0);
      S = __builtin_amdgcn_mfma_f32_32x32x16_bf16(qfh[s], kfl, S, 0, 0, 0);
    }
    const float pm = sM[kh * 32 + l32];
#pragma unroll
    for (int r = 0; r < 16; ++r) {
      float x  = S[r] * 0.125f;
      float ax = fminf(fabsf(x), 30.f);
      float z  = __builtin_amdgcn_exp2f(ax * -2.8853900817779268f);
      float nu = (x >= 0.f) ? z : 1.f;
      float e  = nu * __builtin_amdgcn_rcpf(1.f + z) * -28.853900817779268f;
      float p  = __builtin_amdgcn_exp2f(e) * pm;
      const int row = qh * 32 + (r & 3) + 8 * (r >> 2) + 4 * hl;
      sP[row * PSTR + kh * 32 + l32] = (short)bfhi(p);
    }
    __syncthreads();
#pragma unroll
    for (int s = 0; s < 4; ++s) {
      short8 pf  = *(const short8*)&sP[(qh * 32 + l32) * PSTR + s * 16 + hl * 8];
      const int voff = (kh * 32 + l32) * PSTR + s * 16 + hl * 8;
      short8 vfh = *(const short8*)&sVh[voff];
      short8 vfl = *(const short8*)&sVl[voff];
      accO = __builtin_amdgcn_mfma_f32_32x32x16_bf16(pf, vfh, accO, 0, 0, 0);
      accO = __builtin_amdgcn_mfma_f32_32x32x16_bf16(pf, vfl, accO, 0, 0, 0);
      accD = __builtin_amdgcn_mfma_f32_32x32x16_bf16(pf, ones, accD, 0, 0, 0);
    }
  }
  const size_t obase = (size_t)bh * N_ + qtile * 64 + qh * 32;
#pragma unroll
  for (int r = 0; r < 16; ++r) {
    float den = __shfl(accD[r], lane & 32);
    float inv = (den > 0.f) ? (1.f / den) : 0.f;
    const int row = (r & 3) + 8 * (r >> 2) + 4 * hl;
    Og[(obase + row) * D_ + kh * 32 + l32] = accO[r] * inv;
  }
}

extern "C" void kernel_launch(void* const* d_in, const int* in_sizes, int n_in,
                              void* d_out, int out_size, void* d_ws, size_t ws_size,
                              hipStream_t stream) {
  const float* Q = (const float*)d_in[0];
  const float* K = (const float*)d_in[1];
  const float* V = (const float*)d_in[2];
  const int* mask = (const int*)d_in[3];
  float* out = (float*)d_out;
  dim3 block(256);
  if (ws_size >= (size_t)WS_NEED) {
    u16* wsp  = (u16*)d_ws;
    u16* Khi  = wsp;
    u16* Klo  = wsp + ELEMS;
    u16* VThi = wsp + 2 * (size_t)ELEMS;
    int* idxp = (int*)(wsp + 3 * (size_t)ELEMS);
    int* cntp = idxp + 8 * N_;
    mask_scan<<<dim3(8), block, 0, stream>>>(mask, idxp, cntp);
    conv_kv2<<<dim3(32, 64), block, 0, stream>>>(K, V, idxp, cntp, Khi, Klo, VThi);
    attn_mfma3<<<dim3(16, 64), block, 0, stream>>>(Q, Khi, Klo, VThi, cntp, out);
  } else {
    attn_mfma<<<dim3(32, 64), block, 0, stream>>>(Q, K, V, mask, out);
  }
}